// Round 3
// baseline (99.981 us; speedup 1.0000x reference)
//
#include <hip/hip_runtime.h>
#include <hip/hip_bf16.h>
#include <math.h>

#define LEN_M   131328
#define D_H     256
#define N_MC    64
#define D_P1    513
#define NROW    4096
#define KPAD    512
#define PRED_ELEMS (NROW * N_MC)          // 262144

// ws layout:
//   xb   : bf16 [4096][512]   x cast to bf16, col 512 dropped   (4 MB)
//   wcbt : bf16 [512 c][512 k] combined W transposed, k-contig  (512 KB)
//   wcl  : f32  [512]          d=512 row of combined W          (2 KB)
#define XB_ELEMS   (NROW * KPAD)          // 2097152
#define WCBT_ELEMS (512 * 512)

typedef __attribute__((ext_vector_type(8))) short short8;     // 8 bf16 = 4 VGPR
typedef __attribute__((ext_vector_type(4))) float floatx4;    // mfma acc

// ------------------------------------------------------------------ prep ----
// blocks [0, 8192): xb convert + outputs + wcl (old prep_a)
// blocks [8192, 8256): wcbt transpose build (old prep_b)
__global__ __launch_bounds__(256) void prep_kernel(
    const float* __restrict__ params, const float* __restrict__ x,
    float* __restrict__ out, __hip_bfloat16* __restrict__ xb,
    float* __restrict__ wcl, __hip_bfloat16* __restrict__ wcbt)
{
    __shared__ unsigned short T[64][65];
    const int bid = blockIdx.x;
    const int t   = threadIdx.x;

    if (bid < 8192) {
        int i = bid * 256 + t;
        int row = i >> 9, col = i & 511;
        xb[i] = __float2bfloat16(x[row * D_P1 + col]);
        if (i < PRED_ELEMS) out[i] = 0.0f;                 // zero pred for atomics
        if (i < LEN_M) {
            float m = params[i];
            float v = fmaxf(params[LEN_M + i], 0.0f) + 1e-6f;
            out[PRED_ELEMS + i]         = m;               // m_w0
            out[PRED_ELEMS + LEN_M + i] = v;               // v_w0
            if (i >= 131072) {                             // d == 512 row
                int h = i - 131072;
                wcl[h]       = m;
                wcl[256 + h] = sqrtf(v);
            }
        }
        return;
    }

    // ---- transpose part: build wcbt[c][k] bf16
    const int b2 = bid - 8192;
    const int k0 = (b2 & 7) * 64;
    const int c0 = (b2 >> 3) * 64;
    const int hh = t & 63, kb = t >> 6;
    const bool spart = (c0 >= 256);
    const int hbase = c0 & 255;
    const float* src = params + (spart ? LEN_M : 0);

    #pragma unroll 4
    for (int p = 0; p < 16; ++p) {
        int kk = p * 4 + kb;
        float v = src[(k0 + kk) * 256 + hbase + hh];
        if (spart) v = sqrtf(fmaxf(v, 0.0f) + 1e-6f);
        __hip_bfloat16 b = __float2bfloat16(v);
        T[kk][hh] = *(unsigned short*)&b;
    }
    __syncthreads();

    const int cc = t >> 2, kq = t & 3;
    short8 lo, hi;
    #pragma unroll
    for (int j = 0; j < 8; ++j) lo[j] = (short)T[kq * 16 + j][cc];
    #pragma unroll
    for (int j = 0; j < 8; ++j) hi[j] = (short)T[kq * 16 + 8 + j][cc];
    short* dst = (short*)wcbt + (c0 + cc) * 512 + k0 + kq * 16;
    *(short8*)dst       = lo;
    *(short8*)(dst + 8) = hi;
}

// ------------------------------------------------------------------ main ----
// Grid (4 h-splits, 256 row-tiles). Block: 16 rows x 128 cols (64 A + 64 B).
// 4 waves; wave w: part = w>>1 (0=A/m, 1=B/s), sub-range (w&1)*32, 2 subtiles.
__global__ __launch_bounds__(256) void main_kernel(
    const __hip_bfloat16* __restrict__ xb, const __hip_bfloat16* __restrict__ wcbt,
    const float* __restrict__ wcl, const float* __restrict__ x,
    const float* __restrict__ W1, const float* __restrict__ eps,
    float* __restrict__ out)
{
    __shared__ float Clds[128 * 20];    // [lcol][row(16) + pad4]

    const int t = threadIdx.x;
    const int w = t >> 6, lane = t & 63;
    const int lane15 = lane & 15, quad = lane >> 4;
    const int H  = blockIdx.x;                    // h-range [H*64, H*64+64)
    const int bm = blockIdx.y * 16;

    const int part  = w >> 1;                     // 0 = A(m), 1 = B(sqrt v)
    const int sub   = (w & 1) * 32;
    const int lcol0 = part * 64 + sub;            // block-local col base
    const int gc0   = part * 256 + H * 64 + sub + lane15;   // + s*16

    // early independent loads (overlap with k-loop)
    const float e = eps[lane];
    const int r0 = quad * 4;                      // C rows r0..r0+3
    float xl[4];
    #pragma unroll
    for (int r = 0; r < 4; ++r) xl[r] = x[(bm + r0 + r) * D_P1 + 512];

    const short* ap  = (const short*)xb   + (bm + lane15) * 512 + quad * 8;
    const short* bp0 = (const short*)wcbt + (gc0 +  0) * 512 + quad * 8;
    const short* bp1 = (const short*)wcbt + (gc0 + 16) * 512 + quad * 8;

    floatx4 acc0 = {0.f,0.f,0.f,0.f}, acc1 = acc0;

    #pragma unroll 4
    for (int k0 = 0; k0 < 512; k0 += 32) {
        short8 a  = *(const short8*)(ap  + k0);
        short8 b0 = *(const short8*)(bp0 + k0);
        short8 b1 = *(const short8*)(bp1 + k0);
        acc0 = __builtin_amdgcn_mfma_f32_16x16x32_bf16(a, b0, acc0, 0, 0, 0);
        acc1 = __builtin_amdgcn_mfma_f32_16x16x32_bf16(a, b1, acc1, 0, 0, 0);
    }

    // K=513 remainder (fp32) + C -> LDS [lcol][row] for broadcast reads
    floatx4 accs[2] = {acc0, acc1};
    #pragma unroll
    for (int s = 0; s < 2; ++s) {
        const float wl = wcl[gc0 + s * 16];
        float4 vv;
        vv.x = accs[s][0] + xl[0] * wl;
        vv.y = accs[s][1] + xl[1] * wl;
        vv.z = accs[s][2] + xl[2] * wl;
        vv.w = accs[s][3] + xl[3] * wl;
        const int lcol = lcol0 + s * 16 + lane15;
        *(float4*)&Clds[lcol * 20 + r0] = vv;
    }
    __syncthreads();

    // pred epilogue: lane = m; wave w handles 4 local rows rb..rb+3
    const int rb = w * 4;
    const float init = (H == 0) ? W1[0] : 0.0f;
    float accp[4] = {init, init, init, init};

    #pragma unroll 8
    for (int hl = 0; hl < 64; ++hl) {
        const float w1h = W1[1 + H * 64 + hl];
        const float4 a0 = *(const float4*)&Clds[hl * 20 + rb];
        const float4 b0 = *(const float4*)&Clds[(64 + hl) * 20 + rb];
        accp[0] = fmaf(fmaxf(fmaf(e, b0.x, a0.x), 0.f), w1h, accp[0]);
        accp[1] = fmaf(fmaxf(fmaf(e, b0.y, a0.y), 0.f), w1h, accp[1]);
        accp[2] = fmaf(fmaxf(fmaf(e, b0.z, a0.z), 0.f), w1h, accp[2]);
        accp[3] = fmaf(fmaxf(fmaf(e, b0.w, a0.w), 0.f), w1h, accp[3]);
    }

    float* op = out + (bm + rb) * 64 + lane;
    #pragma unroll
    for (int r = 0; r < 4; ++r)
        unsafeAtomicAdd(op + r * 64, accp[r]);
}

// -------------------------------------------------------------- launch ------
extern "C" void kernel_launch(void* const* d_in, const int* in_sizes, int n_in,
                              void* d_out, int out_size, void* d_ws, size_t ws_size,
                              hipStream_t stream)
{
    const float* params = (const float*)d_in[0];
    const float* W1     = (const float*)d_in[1];
    const float* x      = (const float*)d_in[2];
    const float* eps    = (const float*)d_in[3];
    float* out = (float*)d_out;

    __hip_bfloat16* xb   = (__hip_bfloat16*)d_ws;
    __hip_bfloat16* wcbt = xb + XB_ELEMS;
    float*          wcl  = (float*)(wcbt + WCBT_ELEMS);

    prep_kernel<<<8192 + 64, 256, 0, stream>>>(params, x, out, xb, wcl, wcbt);
    main_kernel<<<dim3(4, 256), 256, 0, stream>>>(xb, wcbt, wcl, x, W1, eps, out);
}

// Round 4
// 89.743 us; speedup vs baseline: 1.1141x; 1.1141x over previous
//
#include <hip/hip_runtime.h>
#include <hip/hip_bf16.h>
#include <math.h>

#define LEN_M   131328
#define D_H     256
#define N_MC    64
#define D_P1    513
#define NROW    4096
#define KPAD    512
#define PRED_ELEMS (NROW * N_MC)          // 262144

// ws layout (floats/bf16):
//   xb      : bf16 [4096][512]    x cast to bf16, col 512 dropped
//   wcbt    : bf16 [512 c][512 k] combined W transposed, k-contig
//   wcl     : f32  [512]          d=512 row of combined W
//   partial : f32  [4][4096][64]  per-H epilogue partial sums
#define XB_ELEMS   (NROW * KPAD)          // 2097152
#define WCBT_ELEMS (512 * 512)

typedef __attribute__((ext_vector_type(8))) short short8;     // 8 bf16 = 4 VGPR
typedef __attribute__((ext_vector_type(4))) float floatx4;    // mfma acc

__device__ __forceinline__ void gl_lds16(const void* g, void* l)
{
    __builtin_amdgcn_global_load_lds(
        (const __attribute__((address_space(1))) unsigned int*)g,
        (__attribute__((address_space(3))) unsigned int*)l, 16, 0, 0);
}

// ------------------------------------------------------------------ prep ----
// blocks [0, 8192): xb convert + m/v outputs + wcl
// blocks [8192, 8256): wcbt transpose build
__global__ __launch_bounds__(256) void prep_kernel(
    const float* __restrict__ params, const float* __restrict__ x,
    float* __restrict__ out, __hip_bfloat16* __restrict__ xb,
    float* __restrict__ wcl, __hip_bfloat16* __restrict__ wcbt)
{
    __shared__ unsigned short T[64][65];
    const int bid = blockIdx.x;
    const int t   = threadIdx.x;

    if (bid < 8192) {
        int i = bid * 256 + t;
        int row = i >> 9, col = i & 511;
        xb[i] = __float2bfloat16(x[row * D_P1 + col]);
        if (i < LEN_M) {
            float m = params[i];
            float v = fmaxf(params[LEN_M + i], 0.0f) + 1e-6f;
            out[PRED_ELEMS + i]         = m;               // m_w0
            out[PRED_ELEMS + LEN_M + i] = v;               // v_w0
            if (i >= 131072) {                             // d == 512 row
                int h = i - 131072;
                wcl[h]       = m;
                wcl[256 + h] = sqrtf(v);
            }
        }
        return;
    }

    // ---- transpose part: build wcbt[c][k] bf16
    const int b2 = bid - 8192;
    const int k0 = (b2 & 7) * 64;
    const int c0 = (b2 >> 3) * 64;
    const int hh = t & 63, kb = t >> 6;
    const bool spart = (c0 >= 256);
    const int hbase = c0 & 255;
    const float* src = params + (spart ? LEN_M : 0);

    #pragma unroll 4
    for (int p = 0; p < 16; ++p) {
        int kk = p * 4 + kb;
        float v = src[(k0 + kk) * 256 + hbase + hh];
        if (spart) v = sqrtf(fmaxf(v, 0.0f) + 1e-6f);
        __hip_bfloat16 b = __float2bfloat16(v);
        T[kk][hh] = *(unsigned short*)&b;
    }
    __syncthreads();

    const int cc = t >> 2, kq = t & 3;
    short8 lo, hi;
    #pragma unroll
    for (int j = 0; j < 8; ++j) lo[j] = (short)T[kq * 16 + j][cc];
    #pragma unroll
    for (int j = 0; j < 8; ++j) hi[j] = (short)T[kq * 16 + 8 + j][cc];
    short* dst = (short*)wcbt + (c0 + cc) * 512 + k0 + kq * 16;
    *(short8*)dst       = lo;
    *(short8*)(dst + 8) = hi;
}

// ------------------------------------------------------------------ main ----
// Grid (4 h-splits, 128 row-tiles). Block tile: 32 rows x 128 cols (64 A+64 B),
// BK=32, single-buffer LDS, global_load_lds width-16 staging (m97 pattern).
// Wave w: rows (w&1)*16..+16, cols (w>>1)*64..+64 (4 subtiles of 16x16).
__global__ __launch_bounds__(256) void main_kernel(
    const __hip_bfloat16* __restrict__ xb, const __hip_bfloat16* __restrict__ wcbt,
    const float* __restrict__ wcl, const float* __restrict__ x,
    const float* __restrict__ W1, const float* __restrict__ eps,
    float* __restrict__ partial)
{
    __shared__ char smem[128 * 36 * 4];          // 18432 B
    short* AsS  = (short*)smem;                  // [32 row][32 k]  2 KB (staging)
    short* BsS  = (short*)(smem + 2048);         // [128 c][32 k]   8 KB (staging)
    float* Clds = (float*)smem;                  // [128 c][36]     (epilogue, aliased)

    const int t = threadIdx.x;
    const int w = t >> 6, lane = t & 63;
    const int lane15 = lane & 15, quad = lane >> 4;
    const int H  = blockIdx.x;                   // h-range [H*64, H*64+64)
    const int bm = blockIdx.y * 32;

    const int rhalf = (w & 1) * 16;
    const int chalf = (w >> 1) * 64;
    const int part  = w >> 1;                    // 0 = A(m), 1 = B(sqrt v)

    const short* xbs = (const short*)xb;
    const short* wbs = (const short*)wcbt;

    // As staging: chunk t (t<128): row=t>>2, kq=t&3 -> LDS t*16
    const short* a_src = xbs + (bm + (t >> 2)) * 512 + (t & 3) * 8;
    void* a_dst = AsS + t * 8;
    // Bs staging: chunks c = t and c = 256+t: lcol=c>>2, kq=c&3 -> LDS c*16
    const int lc0 = t >> 2,        kq0 = t & 3;
    const int lc1 = (256 + t) >> 2, kq1 = t & 3;
    const short* b_src0 = wbs + (((lc0 >> 6) * 256) + H * 64 + (lc0 & 63)) * 512 + kq0 * 8;
    const short* b_src1 = wbs + (((lc1 >> 6) * 256) + H * 64 + (lc1 & 63)) * 512 + kq1 * 8;
    void* b_dst0 = BsS + t * 8;
    void* b_dst1 = BsS + (256 + t) * 8;

    // early independent loads (overlap with k-loop)
    const float e = eps[lane];
    float xl[4], wlv[4];
    #pragma unroll
    for (int r = 0; r < 4; ++r)
        xl[r] = x[(bm + rhalf + quad * 4 + r) * D_P1 + 512];
    #pragma unroll
    for (int s = 0; s < 4; ++s)
        wlv[s] = wcl[part * 256 + H * 64 + s * 16 + lane15];

    floatx4 acc0 = {0.f,0.f,0.f,0.f}, acc1 = acc0, acc2 = acc0, acc3 = acc0;

    const short* a_rd  = AsS + (rhalf + lane15) * 32 + quad * 8;
    const short* b_rd  = BsS + (chalf + lane15) * 32 + quad * 8;

    for (int ks = 0; ks < 16; ++ks) {
        const int k0 = ks * 32;
        if (t < 128) gl_lds16(a_src + k0, a_dst);
        gl_lds16(b_src0 + k0, b_dst0);
        gl_lds16(b_src1 + k0, b_dst1);
        __syncthreads();                         // drains vmcnt -> LDS valid

        short8 a  = *(const short8*)a_rd;
        short8 b0 = *(const short8*)(b_rd);
        short8 b1 = *(const short8*)(b_rd + 16 * 32);
        short8 b2 = *(const short8*)(b_rd + 32 * 32);
        short8 b3 = *(const short8*)(b_rd + 48 * 32);
        acc0 = __builtin_amdgcn_mfma_f32_16x16x32_bf16(a, b0, acc0, 0, 0, 0);
        acc1 = __builtin_amdgcn_mfma_f32_16x16x32_bf16(a, b1, acc1, 0, 0, 0);
        acc2 = __builtin_amdgcn_mfma_f32_16x16x32_bf16(a, b2, acc2, 0, 0, 0);
        acc3 = __builtin_amdgcn_mfma_f32_16x16x32_bf16(a, b3, acc3, 0, 0, 0);
        __syncthreads();                         // before next-iter staging
    }

    // K=513 remainder (fp32) + C -> LDS [lcol][row] for broadcast reads
    floatx4 accs[4] = {acc0, acc1, acc2, acc3};
    const int r0 = rhalf + quad * 4;
    #pragma unroll
    for (int s = 0; s < 4; ++s) {
        float4 vv;
        vv.x = accs[s][0] + xl[0] * wlv[s];
        vv.y = accs[s][1] + xl[1] * wlv[s];
        vv.z = accs[s][2] + xl[2] * wlv[s];
        vv.w = accs[s][3] + xl[3] * wlv[s];
        const int lcol = chalf + s * 16 + lane15;
        *(float4*)&Clds[lcol * 36 + r0] = vv;
    }
    __syncthreads();

    // pred epilogue: lane = m; wave w handles 8 local rows rb..rb+7
    const int rb = w * 8;
    float accp[8] = {0.f,0.f,0.f,0.f,0.f,0.f,0.f,0.f};

    #pragma unroll 8
    for (int hl = 0; hl < 64; ++hl) {
        const float w1h = W1[1 + H * 64 + hl];
        const float4 a0 = *(const float4*)&Clds[hl * 36 + rb];
        const float4 a1 = *(const float4*)&Clds[hl * 36 + rb + 4];
        const float4 b0 = *(const float4*)&Clds[(64 + hl) * 36 + rb];
        const float4 b1 = *(const float4*)&Clds[(64 + hl) * 36 + rb + 4];
        accp[0] = fmaf(fmaxf(fmaf(e, b0.x, a0.x), 0.f), w1h, accp[0]);
        accp[1] = fmaf(fmaxf(fmaf(e, b0.y, a0.y), 0.f), w1h, accp[1]);
        accp[2] = fmaf(fmaxf(fmaf(e, b0.z, a0.z), 0.f), w1h, accp[2]);
        accp[3] = fmaf(fmaxf(fmaf(e, b0.w, a0.w), 0.f), w1h, accp[3]);
        accp[4] = fmaf(fmaxf(fmaf(e, b1.x, a1.x), 0.f), w1h, accp[4]);
        accp[5] = fmaf(fmaxf(fmaf(e, b1.y, a1.y), 0.f), w1h, accp[5]);
        accp[6] = fmaf(fmaxf(fmaf(e, b1.z, a1.z), 0.f), w1h, accp[6]);
        accp[7] = fmaf(fmaxf(fmaf(e, b1.w, a1.w), 0.f), w1h, accp[7]);
    }

    float* op = partial + (H * NROW + bm + rb) * 64 + lane;
    #pragma unroll
    for (int r = 0; r < 8; ++r)
        op[r * 64] = accp[r];
}

// ---------------------------------------------------------------- reduce ----
// out[n][m] = W1[0] + sum_H partial[H][n][m]
__global__ __launch_bounds__(256) void reduce_kernel(
    const float* __restrict__ partial, const float* __restrict__ W1,
    float* __restrict__ out)
{
    const int i = (blockIdx.x * 256 + threadIdx.x) * 4;
    const float4 p0 = *(const float4*)(partial + i);
    const float4 p1 = *(const float4*)(partial + PRED_ELEMS + i);
    const float4 p2 = *(const float4*)(partial + 2 * PRED_ELEMS + i);
    const float4 p3 = *(const float4*)(partial + 3 * PRED_ELEMS + i);
    const float b = W1[0];
    float4 o;
    o.x = b + ((p0.x + p1.x) + (p2.x + p3.x));
    o.y = b + ((p0.y + p1.y) + (p2.y + p3.y));
    o.z = b + ((p0.z + p1.z) + (p2.z + p3.z));
    o.w = b + ((p0.w + p1.w) + (p2.w + p3.w));
    *(float4*)(out + i) = o;
}

// -------------------------------------------------------------- launch ------
extern "C" void kernel_launch(void* const* d_in, const int* in_sizes, int n_in,
                              void* d_out, int out_size, void* d_ws, size_t ws_size,
                              hipStream_t stream)
{
    const float* params = (const float*)d_in[0];
    const float* W1     = (const float*)d_in[1];
    const float* x      = (const float*)d_in[2];
    const float* eps    = (const float*)d_in[3];
    float* out = (float*)d_out;

    __hip_bfloat16* xb   = (__hip_bfloat16*)d_ws;
    __hip_bfloat16* wcbt = xb + XB_ELEMS;
    float*          wcl  = (float*)(wcbt + WCBT_ELEMS);
    float*          part = wcl + 512;

    prep_kernel<<<8192 + 64, 256, 0, stream>>>(params, x, out, xb, wcl, wcbt);
    main_kernel<<<dim3(4, 128), 256, 0, stream>>>(xb, wcbt, wcl, x, W1, eps, part);
    reduce_kernel<<<PRED_ELEMS / 1024, 256, 0, stream>>>(part, W1, out);
}

// Round 5
// 85.212 us; speedup vs baseline: 1.1733x; 1.0532x over previous
//
#include <hip/hip_runtime.h>
#include <hip/hip_bf16.h>
#include <math.h>

#define LEN_M   131328
#define D_P1    513
#define NROW    4096
#define PRED_ELEMS (NROW * 64)            // 262144

// ws layout: wcbt bf16 [512 c][512 k], XOR-swizzled 16B chunks (512 KB). Only ws use.
typedef __attribute__((ext_vector_type(8))) short short8;     // 8 bf16 = 4 VGPR
typedef __attribute__((ext_vector_type(4))) float floatx4;    // mfma acc
typedef __attribute__((ext_vector_type(2))) float v2f;        // packed fp32

__device__ __forceinline__ void gl_lds16(const void* g, void* l)
{
    __builtin_amdgcn_global_load_lds(
        (const __attribute__((address_space(1))) unsigned int*)g,
        (__attribute__((address_space(3))) unsigned int*)l, 16, 0, 0);
}

__device__ __forceinline__ unsigned short bf16b(float f)
{
    __hip_bfloat16 h = __float2bfloat16(f);
    return *(unsigned short*)&h;
}

// ------------------------------------------------------------------ prep ----
// blocks [0,1024): zero pred region + write m_w0 / v_w0 outputs
// blocks [1024,1088): build swizzled wcbt[c][k] bf16 via LDS transpose
__global__ __launch_bounds__(256) void prep_kernel(
    const float* __restrict__ params, float* __restrict__ out,
    __hip_bfloat16* __restrict__ wcbt)
{
    __shared__ unsigned short T[64][65];
    const int bid = blockIdx.x;
    const int t   = threadIdx.x;

    if (bid < 1024) {
        int i = bid * 256 + t;
        out[i] = 0.0f;                                   // pred accum base
        if (i < LEN_M) {
            float m = params[i];
            float v = fmaxf(params[LEN_M + i], 0.0f) + 1e-6f;
            out[PRED_ELEMS + i]         = m;             // m_w0
            out[PRED_ELEMS + LEN_M + i] = v;             // v_w0
        }
        return;
    }

    const int b2 = bid - 1024;
    const int k0 = (b2 & 7) * 64;
    const int c0 = (b2 >> 3) * 64;
    const int hh = t & 63, kb = t >> 6;
    const bool spart = (c0 >= 256);
    const int hbase = c0 & 255;
    const float* src = params + (spart ? LEN_M : 0);

    #pragma unroll 4
    for (int p = 0; p < 16; ++p) {
        int kk = p * 4 + kb;
        float v = src[(k0 + kk) * 256 + hbase + hh];
        if (spart) v = sqrtf(fmaxf(v, 0.0f) + 1e-6f);
        T[kk][hh] = bf16b(v);
    }
    __syncthreads();

    const int cc = t >> 2, kq = t & 3;
    short8 lo, hi;
    #pragma unroll
    for (int j = 0; j < 8; ++j) lo[j] = (short)T[kq * 16 + j][cc];
    #pragma unroll
    for (int j = 0; j < 8; ++j) hi[j] = (short)T[kq * 16 + 8 + j][cc];

    const int cR  = c0 + cc;
    const int swz = (cR >> 1) & 3;
    const int g1  = (k0 >> 3) + 2 * kq;                  // 16B-chunk idx in row
    const int g2  = g1 + 1;
    const int d1  = cR * 64 + (g1 & ~3) + ((g1 & 3) ^ swz);
    const int d2  = cR * 64 + (g2 & ~3) + ((g2 & 3) ^ swz);
    short* wb = (short*)wcbt;
    *(short8*)(wb + d1 * 8) = lo;
    *(short8*)(wb + d2 * 8) = hi;
}

// ------------------------------------------------------------------ main ----
// Grid (4 H, 128 bm). Block: 32 rows x 64 h (=128 cols: m-part + s-part).
// BK=32, 16 iters. A staged from x fp32 (in-reg bf16 cvt), B via global_load_lds
// from pre-swizzled wcbt. Epilogue: fixup k=512, C->LDS, packed pred, atomics.
__global__ __launch_bounds__(256) void main_kernel(
    const __hip_bfloat16* __restrict__ wcbt, const float* __restrict__ params,
    const float* __restrict__ x, const float* __restrict__ W1,
    const float* __restrict__ eps, float* __restrict__ out)
{
    __shared__ char smem[128 * 36 * 4];                  // 18432 B
    short* Bs   = (short*)smem;                          // [128 lc][32 k] 8 KB
    short* As   = (short*)(smem + 8192);                 // [32 r][32 k]   2 KB
    float* Clds = (float*)smem;                          // [128 lc][36] (alias)

    const int t = threadIdx.x;
    const int w4 = t >> 6, lane = t & 63;
    const int lane15 = lane & 15, quad = lane >> 4;
    const int H  = blockIdx.x;                           // h-range [H*64, +64)
    const int bm = blockIdx.y * 32;

    // ---- B staging: 2 chunks/thread/iter, identity copy (swizzle pre-baked)
    const short* wb = (const short*)wcbt;
    const short* bsrc0; const short* bsrc1; short* bdst0; short* bdst1;
    {
        int ch0 = t, ch1 = 256 + t;
        int lc0 = ch0 >> 2, qs0 = ch0 & 3;
        int lc1 = ch1 >> 2, qs1 = ch1 & 3;
        int c0g = H * 64 + lc0 + ((lc0 >> 6) * 192);
        int c1g = H * 64 + lc1 + ((lc1 >> 6) * 192);
        bsrc0 = wb + (c0g * 64 + qs0) * 8;
        bsrc1 = wb + (c1g * 64 + qs1) * 8;
        bdst0 = Bs + ch0 * 8;
        bdst1 = Bs + ch1 * 8;
    }

    // ---- A staging: thread -> (row ar, 4-float group asub)
    const int ar = t >> 3, asub = t & 7;
    const int aq = asub >> 1, ahalf = asub & 1;
    const float* axp = x + (bm + ar) * D_P1 + asub * 4;
    unsigned short* adst = (unsigned short*)As + ar * 32
                         + ((aq ^ ((ar >> 1) & 3)) * 8) + ahalf * 4;

    // ---- early independent loads
    const float e = eps[lane];
    float xl[2][4];
    #pragma unroll
    for (int rh = 0; rh < 2; ++rh)
        #pragma unroll
        for (int i = 0; i < 4; ++i)
            xl[rh][i] = x[(bm + rh * 16 + quad * 4 + i) * D_P1 + 512];
    float wl[2];
    #pragma unroll
    for (int s = 0; s < 2; ++s) {
        int lc = w4 * 32 + s * 16 + lane15;
        int c  = H * 64 + lc + ((lc >> 6) * 192);
        wl[s] = (c < 256) ? params[131072 + c]
                          : sqrtf(fmaxf(params[LEN_M + 131072 + (c - 256)], 0.0f) + 1e-6f);
    }

    // ---- fragment read pointers (2-way bank aliasing = free)
    const short* afp[2]; const short* bfp[2];
    #pragma unroll
    for (int rh = 0; rh < 2; ++rh) {
        int row = rh * 16 + lane15;
        afp[rh] = As + row * 32 + ((quad ^ ((row >> 1) & 3)) * 8);
    }
    #pragma unroll
    for (int s = 0; s < 2; ++s) {
        int lc = w4 * 32 + s * 16 + lane15;
        bfp[s] = Bs + lc * 32 + ((quad ^ ((lc >> 1) & 3)) * 8);
    }

    floatx4 acc00 = {0.f,0.f,0.f,0.f}, acc01 = acc00, acc10 = acc00, acc11 = acc00;

    for (int ks = 0; ks < 16; ++ks) {
        gl_lds16(bsrc0 + ks * 32, bdst0);
        gl_lds16(bsrc1 + ks * 32, bdst1);
        // A: 4 scalar dword loads (rows not 16B-aligned: 513-stride), cvt, 8B ds_write
        float f0 = axp[ks * 32 + 0], f1 = axp[ks * 32 + 1];
        float f2 = axp[ks * 32 + 2], f3 = axp[ks * 32 + 3];
        ushort4 pk;
        pk.x = bf16b(f0); pk.y = bf16b(f1); pk.z = bf16b(f2); pk.w = bf16b(f3);
        *(ushort4*)adst = pk;
        __syncthreads();                                 // staging visible

        short8 a0 = *(const short8*)afp[0];
        short8 a1 = *(const short8*)afp[1];
        short8 b0 = *(const short8*)bfp[0];
        short8 b1 = *(const short8*)bfp[1];
        acc00 = __builtin_amdgcn_mfma_f32_16x16x32_bf16(a0, b0, acc00, 0, 0, 0);
        acc01 = __builtin_amdgcn_mfma_f32_16x16x32_bf16(a0, b1, acc01, 0, 0, 0);
        acc10 = __builtin_amdgcn_mfma_f32_16x16x32_bf16(a1, b0, acc10, 0, 0, 0);
        acc11 = __builtin_amdgcn_mfma_f32_16x16x32_bf16(a1, b1, acc11, 0, 0, 0);
        __syncthreads();                                 // frags consumed
    }

    // ---- fixup k=512 + C -> LDS [lc][r] (alias over staging buffers)
    floatx4 accs[2][2] = {{acc00, acc01}, {acc10, acc11}};
    #pragma unroll
    for (int rh = 0; rh < 2; ++rh)
        #pragma unroll
        for (int s = 0; s < 2; ++s) {
            float4 o;
            o.x = accs[rh][s][0] + xl[rh][0] * wl[s];
            o.y = accs[rh][s][1] + xl[rh][1] * wl[s];
            o.z = accs[rh][s][2] + xl[rh][2] * wl[s];
            o.w = accs[rh][s][3] + xl[rh][3] * wl[s];
            int lc = w4 * 32 + s * 16 + lane15;
            int r0 = rh * 16 + quad * 4;
            *(float4*)&Clds[lc * 36 + r0] = o;
        }
    __syncthreads();

    // ---- pred epilogue: lane = m; wave w4 rows rb..rb+7; packed fp32 math
    const int rb = w4 * 8;
    const float binit = (H == 0) ? W1[0] : 0.0f;
    v2f accp[4];
    #pragma unroll
    for (int j = 0; j < 4; ++j) accp[j] = (v2f){binit, binit};
    const v2f e2 = {e, e};
    const v2f z2 = {0.f, 0.f};

    #pragma unroll 4
    for (int lh = 0; lh < 64; ++lh) {
        const float w1h = W1[1 + H * 64 + lh];
        const v2f w2 = {w1h, w1h};
        const v2f* ap = (const v2f*)&Clds[lh * 36 + rb];
        const v2f* bp = (const v2f*)&Clds[(64 + lh) * 36 + rb];
        #pragma unroll
        for (int j = 0; j < 4; ++j) {
            v2f t2 = __builtin_elementwise_fma(e2, bp[j], ap[j]);
            t2 = __builtin_elementwise_max(t2, z2);
            accp[j] = __builtin_elementwise_fma(t2, w2, accp[j]);
        }
    }

    float* op = out + (bm + rb) * 64 + lane;
    #pragma unroll
    for (int j = 0; j < 4; ++j) {
        unsafeAtomicAdd(op + (2 * j) * 64,     accp[j].x);
        unsafeAtomicAdd(op + (2 * j + 1) * 64, accp[j].y);
    }
}

// -------------------------------------------------------------- launch ------
extern "C" void kernel_launch(void* const* d_in, const int* in_sizes, int n_in,
                              void* d_out, int out_size, void* d_ws, size_t ws_size,
                              hipStream_t stream)
{
    const float* params = (const float*)d_in[0];
    const float* W1     = (const float*)d_in[1];
    const float* x      = (const float*)d_in[2];
    const float* eps    = (const float*)d_in[3];
    float* out = (float*)d_out;
    __hip_bfloat16* wcbt = (__hip_bfloat16*)d_ws;

    prep_kernel<<<1024 + 64, 256, 0, stream>>>(params, out, wcbt);
    main_kernel<<<dim3(4, 128), 256, 0, stream>>>(wcbt, params, x, W1, eps, out);
}

// Round 6
// 84.826 us; speedup vs baseline: 1.1787x; 1.0045x over previous
//
#include <hip/hip_runtime.h>
#include <hip/hip_bf16.h>
#include <math.h>

#define LEN_M   131328
#define D_P1    513
#define NROW    4096
#define PRED_ELEMS (NROW * 64)            // 262144

// ws layout: wcbt bf16 [512 c][512 k], XOR-swizzled 16B chunks (512 KB).
typedef __attribute__((ext_vector_type(8))) short short8;     // 8 bf16 = 4 VGPR
typedef __attribute__((ext_vector_type(4))) float floatx4;    // mfma acc
typedef __attribute__((ext_vector_type(2))) float v2f;        // packed fp32

__device__ __forceinline__ void gl_lds16(const void* g, void* l)
{
    __builtin_amdgcn_global_load_lds(
        (const __attribute__((address_space(1))) unsigned int*)g,
        (__attribute__((address_space(3))) unsigned int*)l, 16, 0, 0);
}

__device__ __forceinline__ unsigned short bf16b(float f)
{
    __hip_bfloat16 h = __float2bfloat16(f);
    return *(unsigned short*)&h;
}

// ------------------------------------------------------------------ prep ----
// blocks [0,1024): zero pred region + write m_w0 / v_w0 outputs
// blocks [1024,1088): build swizzled wcbt[c][k] bf16 via LDS transpose
__global__ __launch_bounds__(256) void prep_kernel(
    const float* __restrict__ params, float* __restrict__ out,
    __hip_bfloat16* __restrict__ wcbt)
{
    __shared__ unsigned short T[64][65];
    const int bid = blockIdx.x;
    const int t   = threadIdx.x;

    if (bid < 1024) {
        int i = bid * 256 + t;
        out[i] = 0.0f;                                   // pred accum base
        if (i < LEN_M) {
            float m = params[i];
            float v = fmaxf(params[LEN_M + i], 0.0f) + 1e-6f;
            out[PRED_ELEMS + i]         = m;             // m_w0
            out[PRED_ELEMS + LEN_M + i] = v;             // v_w0
        }
        return;
    }

    const int b2 = bid - 1024;
    const int k0 = (b2 & 7) * 64;
    const int c0 = (b2 >> 3) * 64;
    const int hh = t & 63, kb = t >> 6;
    const bool spart = (c0 >= 256);
    const int hbase = c0 & 255;
    const float* src = params + (spart ? LEN_M : 0);

    #pragma unroll 4
    for (int p = 0; p < 16; ++p) {
        int kk = p * 4 + kb;
        float v = src[(k0 + kk) * 256 + hbase + hh];
        if (spart) v = sqrtf(fmaxf(v, 0.0f) + 1e-6f);
        T[kk][hh] = bf16b(v);
    }
    __syncthreads();

    const int cc = t >> 2, kq = t & 3;
    short8 lo, hi;
    #pragma unroll
    for (int j = 0; j < 8; ++j) lo[j] = (short)T[kq * 16 + j][cc];
    #pragma unroll
    for (int j = 0; j < 8; ++j) hi[j] = (short)T[kq * 16 + 8 + j][cc];

    const int cR  = c0 + cc;
    const int swz = (cR >> 1) & 3;
    const int g1  = (k0 >> 3) + 2 * kq;                  // 16B-chunk idx in row
    const int g2  = g1 + 1;
    const int d1  = cR * 64 + (g1 & ~3) + ((g1 & 3) ^ swz);
    const int d2  = cR * 64 + (g2 & ~3) + ((g2 & 3) ^ swz);
    short* wb = (short*)wcbt;
    *(short8*)(wb + d1 * 8) = lo;
    *(short8*)(wb + d2 * 8) = hi;
}

// ------------------------------------------------------------------ main ----
// Grid (4 H, 128 bm). Block: 32 rows x 128 cols (64 m + 64 s).
// A-panel (32x512) staged to LDS ONCE before the loop; B double-buffered via
// global_load_lds with one barrier per iter (prefetch ks+1 over compute ks).
__global__ __launch_bounds__(256) void main_kernel(
    const __hip_bfloat16* __restrict__ wcbt, const float* __restrict__ params,
    const float* __restrict__ x, const float* __restrict__ W1,
    const float* __restrict__ eps, float* __restrict__ out)
{
    __shared__ char smem[49152];
    char*  Bs   = smem;                                  // 2 x [128 lc][32 k] 16 KB
    char*  As   = smem + 16384;                          // [32 r][512 k]     32 KB
    float* Clds = (float*)(smem + 16384);                // [128 lc][36] (alias A)

    const int t = threadIdx.x;
    const int w4 = t >> 6, lane = t & 63;
    const int lane15 = lane & 15, quad = lane >> 4;
    const int H  = blockIdx.x;                           // h-range [H*64, +64)
    const int bm = blockIdx.y * 32;

    // ---- B staging source/dest (identity copy; swizzle pre-baked in wcbt)
    const short* wb = (const short*)wcbt;
    const short* bsrc0; const short* bsrc1;
    {
        int ch0 = t, ch1 = 256 + t;
        int lc0 = ch0 >> 2, qs0 = ch0 & 3;
        int lc1 = ch1 >> 2, qs1 = ch1 & 3;
        int c0g = H * 64 + lc0 + ((lc0 >> 6) * 192);
        int c1g = H * 64 + lc1 + ((lc1 >> 6) * 192);
        bsrc0 = wb + (c0g * 64 + qs0) * 8;
        bsrc1 = wb + (c1g * 64 + qs1) * 8;
    }
    char* bd0 = Bs + t * 16;
    char* bd1 = Bs + 4096 + t * 16;

    // ---- pre-stage B slice 0 into buf 0
    gl_lds16(bsrc0, bd0);
    gl_lds16(bsrc1, bd1);

    // ---- A panel staging: [32 r][512 k] bf16, 16B chunks XOR-swizzled (r&7)
    {
        const int ar = t >> 3, a8 = t & 7;
        const float* axp = x + (bm + ar) * D_P1;
        unsigned short* arow = (unsigned short*)As + ar * 512;
        #pragma unroll 4
        for (int ks = 0; ks < 16; ++ks) {
            int k = ks * 32 + a8 * 4;
            float f0 = axp[k], f1 = axp[k + 1], f2 = axp[k + 2], f3 = axp[k + 3];
            int chunk = k >> 3;
            int half  = a8 & 1;
            int cs = (chunk & ~7) | ((chunk & 7) ^ (ar & 7));
            ushort4 pk;
            pk.x = bf16b(f0); pk.y = bf16b(f1); pk.z = bf16b(f2); pk.w = bf16b(f3);
            *(ushort4*)(arow + cs * 8 + half * 4) = pk;
        }
    }

    // ---- early independent loads (k=512 fixup + eps)
    const float e = eps[lane];
    float xl[2][4];
    #pragma unroll
    for (int rh = 0; rh < 2; ++rh)
        #pragma unroll
        for (int i = 0; i < 4; ++i)
            xl[rh][i] = x[(bm + rh * 16 + quad * 4 + i) * D_P1 + 512];
    float wl[2];
    #pragma unroll
    for (int s = 0; s < 2; ++s) {
        int lc = w4 * 32 + s * 16 + lane15;
        int c  = H * 64 + lc + ((lc >> 6) * 192);
        wl[s] = (c < 256) ? params[131072 + c]
                          : sqrtf(fmaxf(params[LEN_M + 131072 + (c - 256)], 0.0f) + 1e-6f);
    }

    // ---- B fragment byte offsets (within a buffer)
    int bfo[2];
    #pragma unroll
    for (int s = 0; s < 2; ++s) {
        int lc = w4 * 32 + s * 16 + lane15;
        bfo[s] = lc * 64 + ((quad ^ ((lc >> 1) & 3)) * 16);
    }
    const int ax7 = lane15 & 7;

    floatx4 acc00 = {0.f,0.f,0.f,0.f}, acc01 = acc00, acc10 = acc00, acc11 = acc00;

    __syncthreads();                                     // A panel + B slice 0 ready

    for (int ks = 0; ks < 16; ++ks) {
        // prefetch B slice ks+1 into other buffer (iter 15: harmless overread)
        const int nb = (ks + 1) & 1;
        gl_lds16(bsrc0 + (ks + 1) * 32, bd0 + nb * 8192);
        gl_lds16(bsrc1 + (ks + 1) * 32, bd1 + nb * 8192);

        // A frags: row-major swizzled panel
        const int cs16 = ((ks >> 1) * 8 + (((ks & 1) * 4 + quad) ^ ax7)) * 16;
        short8 a0 = *(const short8*)(As + lane15 * 1024 + cs16);
        short8 a1 = *(const short8*)(As + (16 + lane15) * 1024 + cs16);
        // B frags from current buffer
        const char* Bb = Bs + (ks & 1) * 8192;
        short8 b0 = *(const short8*)(Bb + bfo[0]);
        short8 b1 = *(const short8*)(Bb + bfo[1]);

        acc00 = __builtin_amdgcn_mfma_f32_16x16x32_bf16(a0, b0, acc00, 0, 0, 0);
        acc01 = __builtin_amdgcn_mfma_f32_16x16x32_bf16(a0, b1, acc01, 0, 0, 0);
        acc10 = __builtin_amdgcn_mfma_f32_16x16x32_bf16(a1, b0, acc10, 0, 0, 0);
        acc11 = __builtin_amdgcn_mfma_f32_16x16x32_bf16(a1, b1, acc11, 0, 0, 0);
        __syncthreads();                                 // next buffer staged & safe
    }

    // ---- fixup k=512 + C -> LDS [lc][r] (aliases A panel; all A reads done)
    floatx4 accs[2][2] = {{acc00, acc01}, {acc10, acc11}};
    #pragma unroll
    for (int rh = 0; rh < 2; ++rh)
        #pragma unroll
        for (int s = 0; s < 2; ++s) {
            float4 o;
            o.x = accs[rh][s][0] + xl[rh][0] * wl[s];
            o.y = accs[rh][s][1] + xl[rh][1] * wl[s];
            o.z = accs[rh][s][2] + xl[rh][2] * wl[s];
            o.w = accs[rh][s][3] + xl[rh][3] * wl[s];
            int lc = w4 * 32 + s * 16 + lane15;
            int r0 = rh * 16 + quad * 4;
            *(float4*)&Clds[lc * 36 + r0] = o;
        }
    __syncthreads();

    // ---- pred epilogue: lane = m; wave w4 rows rb..rb+7; packed fp32 math
    const int rb = w4 * 8;
    const float binit = (H == 0) ? W1[0] : 0.0f;
    v2f accp[4];
    #pragma unroll
    for (int j = 0; j < 4; ++j) accp[j] = (v2f){binit, binit};
    const v2f e2 = {e, e};
    const v2f z2 = {0.f, 0.f};

    #pragma unroll 4
    for (int lh = 0; lh < 64; ++lh) {
        const float w1h = W1[1 + H * 64 + lh];
        const v2f w2 = {w1h, w1h};
        const v2f* ap = (const v2f*)&Clds[lh * 36 + rb];
        const v2f* bp = (const v2f*)&Clds[(64 + lh) * 36 + rb];
        #pragma unroll
        for (int j = 0; j < 4; ++j) {
            v2f t2 = __builtin_elementwise_fma(e2, bp[j], ap[j]);
            t2 = __builtin_elementwise_max(t2, z2);
            accp[j] = __builtin_elementwise_fma(t2, w2, accp[j]);
        }
    }

    float* op = out + (bm + rb) * 64 + lane;
    #pragma unroll
    for (int j = 0; j < 4; ++j) {
        unsafeAtomicAdd(op + (2 * j) * 64,     accp[j].x);
        unsafeAtomicAdd(op + (2 * j + 1) * 64, accp[j].y);
    }
}

// -------------------------------------------------------------- launch ------
extern "C" void kernel_launch(void* const* d_in, const int* in_sizes, int n_in,
                              void* d_out, int out_size, void* d_ws, size_t ws_size,
                              hipStream_t stream)
{
    const float* params = (const float*)d_in[0];
    const float* W1     = (const float*)d_in[1];
    const float* x      = (const float*)d_in[2];
    const float* eps    = (const float*)d_in[3];
    float* out = (float*)d_out;
    __hip_bfloat16* wcbt = (__hip_bfloat16*)d_ws;

    prep_kernel<<<1024 + 64, 256, 0, stream>>>(params, out, wcbt);
    main_kernel<<<dim3(4, 128), 256, 0, stream>>>(wcbt, params, x, W1, eps, out);
}